// Round 1
// baseline (302.835 us; speedup 1.0000x reference)
//
#include <hip/hip_runtime.h>

#define EMPTY_VAL (-100.0f)

// Geometry: x[B=8, C=8, D=128, H=128, W=128] fp32
constexpr int CH_FLOATS     = 128 * 128 * 128;      // 2,097,152 floats / channel
constexpr int CH_VEC4       = CH_FLOATS / 4;        // 524,288 float4 / channel
constexpr int THREADS       = 256;
constexpr int V4_PER_THREAD = 16;
constexpr int BLOCK_VEC4    = THREADS * V4_PER_THREAD;  // 4096
constexpr int BLOCKS_PER_CH = CH_VEC4 / BLOCK_VEC4;     // 128
constexpr int NCH           = 8 * 8;                    // 64 (b,c) channels
constexpr int TOTAL_BLOCKS  = NCH * BLOCKS_PER_CH;      // 8192

// CLASS_RELATIONS = {0:[1,2],1:[0,3],2:[4,5],3:[6,7],4:[0,1],5:[2,3],6:[4,5],7:[6,0]}
__constant__ int REL0[8] = {1, 0, 4, 6, 0, 2, 4, 6};
__constant__ int REL1[8] = {2, 3, 5, 7, 1, 3, 5, 0};

// flags[ch*2+0] = any_empty, flags[ch*2+1] = any_nonempty (both start 0)
__global__ __launch_bounds__(THREADS) void flags_kernel(
    const float* __restrict__ x, int* __restrict__ flags) {
  const int blk   = blockIdx.x;
  const int ch    = blk / BLOCKS_PER_CH;
  const int chunk = blk % BLOCKS_PER_CH;
  const int tid   = threadIdx.x;

  const float4* p = reinterpret_cast<const float4*>(x) +
                    (size_t)ch * CH_VEC4 + (size_t)chunk * BLOCK_VEC4;

  bool any_empty = false, any_nonempty = false;
#pragma unroll
  for (int i = 0; i < V4_PER_THREAD; ++i) {
    float4 v = p[tid + i * THREADS];
    const bool e0 = (v.x == EMPTY_VAL), e1 = (v.y == EMPTY_VAL);
    const bool e2 = (v.z == EMPTY_VAL), e3 = (v.w == EMPTY_VAL);
    any_empty    |= (e0 | e1 | e2 | e3);
    any_nonempty |= (!e0 | !e1 | !e2 | !e3);
  }

  // wave64 reduce, then cross-wave via LDS, then one atomic pair per block
  const bool we = __any(any_empty);
  const bool wn = __any(any_nonempty);

  __shared__ int s_e, s_n;
  if (tid == 0) { s_e = 0; s_n = 0; }
  __syncthreads();
  if ((tid & 63) == 0) {
    if (we) atomicOr(&s_e, 1);
    if (wn) atomicOr(&s_n, 1);
  }
  __syncthreads();
  if (tid == 0) {
    if (s_e) atomicOr(&flags[ch * 2 + 0], 1);
    if (s_n) atomicOr(&flags[ch * 2 + 1], 1);
  }
}

__global__ __launch_bounds__(THREADS) void out_kernel(
    const float* __restrict__ x, const int* __restrict__ flags,
    float* __restrict__ out) {
  const int blk   = blockIdx.x;
  const int ch    = blk / BLOCKS_PER_CH;
  const int chunk = blk % BLOCKS_PER_CH;
  const int b     = ch >> 3;
  const int c     = ch & 7;
  const int tid   = threadIdx.x;

  const size_t base = (size_t)ch * CH_VEC4 + (size_t)chunk * BLOCK_VEC4;
  float4* o = reinterpret_cast<float4*>(out) + base;

  const float4 empty4 = make_float4(EMPTY_VAL, EMPTY_VAL, EMPTY_VAL, EMPTY_VAL);

  // all_empty <=> no non-empty voxel seen
  const bool all_empty = (flags[ch * 2 + 1] == 0);
  if (!all_empty) {
#pragma unroll
    for (int i = 0; i < V4_PER_THREAD; ++i) o[tid + i * THREADS] = empty4;
    return;
  }

  const int r0 = REL0[c], r1 = REL1[c];
  const bool v0 = (flags[(b * 8 + r0) * 2 + 0] == 0);  // rel fully labeled
  const bool v1 = (flags[(b * 8 + r1) * 2 + 0] == 0);

  if (!v0 && !v1) {
#pragma unroll
    for (int i = 0; i < V4_PER_THREAD; ++i) o[tid + i * THREADS] = empty4;
    return;
  }

  const float4* p0 = reinterpret_cast<const float4*>(x) +
                     ((size_t)(b * 8 + r0) * CH_VEC4 + (size_t)chunk * BLOCK_VEC4);
  const float4* p1 = reinterpret_cast<const float4*>(x) +
                     ((size_t)(b * 8 + r1) * CH_VEC4 + (size_t)chunk * BLOCK_VEC4);

  const float4 zero4 = make_float4(0.f, 0.f, 0.f, 0.f);
#pragma unroll
  for (int i = 0; i < V4_PER_THREAD; ++i) {
    const int idx = tid + i * THREADS;
    const float4 a = v0 ? p0[idx] : zero4;   // block-uniform predicate
    const float4 q = v1 ? p1[idx] : zero4;
    float4 r;
    r.x = (a.x > 0.f || q.x > 0.f) ? 0.f : EMPTY_VAL;
    r.y = (a.y > 0.f || q.y > 0.f) ? 0.f : EMPTY_VAL;
    r.z = (a.z > 0.f || q.z > 0.f) ? 0.f : EMPTY_VAL;
    r.w = (a.w > 0.f || q.w > 0.f) ? 0.f : EMPTY_VAL;
    o[idx] = r;
  }
}

extern "C" void kernel_launch(void* const* d_in, const int* in_sizes, int n_in,
                              void* d_out, int out_size, void* d_ws, size_t ws_size,
                              hipStream_t stream) {
  const float* x = (const float*)d_in[0];
  float* out     = (float*)d_out;
  int* flags     = (int*)d_ws;

  hipMemsetAsync(flags, 0, NCH * 2 * sizeof(int), stream);
  flags_kernel<<<TOTAL_BLOCKS, THREADS, 0, stream>>>(x, flags);
  out_kernel<<<TOTAL_BLOCKS, THREADS, 0, stream>>>(x, flags, out);
}

// Round 3
// 215.689 us; speedup vs baseline: 1.4040x; 1.4040x over previous
//
#include <hip/hip_runtime.h>
#include <stdint.h>

#define EMPTY_VAL (-100.0f)

// native vector type: __builtin_nontemporal_* rejects HIP_vector_type
typedef float f4 __attribute__((ext_vector_type(4)));

// Geometry: x[B=8, C=8, D=128, H=128, W=128] fp32
constexpr int B = 8, C = 8;
constexpr int VOX       = 128 * 128 * 128;   // voxels per channel
constexpr int CH_VEC4   = VOX / 4;           // 524,288 float4 per channel
constexpr int THREADS   = 256;
constexpr int ITERS     = 8;                 // float4-groups per thread
constexpr int V4_PER_BLOCK    = THREADS * ITERS;        // 2048 float4 = 8192 voxels
constexpr int BLOCKS_PER_BATCH = CH_VEC4 / V4_PER_BLOCK; // 256
constexpr int GRID      = B * BLOCKS_PER_BATCH;          // 2048

// CLASS_RELATIONS = {0:[1,2],1:[0,3],2:[4,5],3:[6,7],4:[0,1],5:[2,3],6:[4,5],7:[6,0]}
constexpr int REL0c[8] = {1, 0, 4, 6, 0, 2, 4, 6};
constexpr int REL1c[8] = {2, 3, 5, 7, 1, 3, 5, 0};

// ---------------- fast path: mask in d_ws ----------------
// Pass 1: stream x once; write 8-bit-per-voxel positivity mask (uint per 4 vox)
// and bitpacked per-batch anyEmpty / anyNonempty channel flags.
__global__ __launch_bounds__(THREADS) void mask_kernel(
    const float* __restrict__ x, uint32_t* __restrict__ mask,
    int* __restrict__ flagsE, int* __restrict__ flagsN) {
  const int b     = blockIdx.x / BLOCKS_PER_BATCH;
  const int chunk = blockIdx.x % BLOCKS_PER_BATCH;
  const int tid   = threadIdx.x;
  const size_t vb4 = (size_t)chunk * V4_PER_BLOCK;

  const f4* xb = reinterpret_cast<const f4*>(x) + (size_t)b * C * CH_VEC4;
  uint32_t* mb = mask + (size_t)b * CH_VEC4;

  uint32_t anyE = 0, anyN = 0;  // bit c

  for (int it = 0; it < ITERS; ++it) {
    const size_t i4 = vb4 + (size_t)it * THREADS + tid;
    uint32_t m = 0;
#pragma unroll
    for (int c = 0; c < C; ++c) {
      const f4 v = __builtin_nontemporal_load(xb + ((size_t)c * CH_VEC4 + i4));
      uint32_t pos = (v.x > 0.f ? 0x00000001u : 0u) |
                     (v.y > 0.f ? 0x00000100u : 0u) |
                     (v.z > 0.f ? 0x00010000u : 0u) |
                     (v.w > 0.f ? 0x01000000u : 0u);
      m |= pos << c;
      const bool e0 = (v.x == EMPTY_VAL), e1 = (v.y == EMPTY_VAL);
      const bool e2 = (v.z == EMPTY_VAL), e3 = (v.w == EMPTY_VAL);
      if (e0 | e1 | e2 | e3)             anyE |= (1u << c);
      if ((!e0) | (!e1) | (!e2) | (!e3)) anyN |= (1u << c);
    }
    __builtin_nontemporal_store(m, mb + i4);
  }

  // wave-level OR reduce, then one LDS combine, then one global atomic per block
#pragma unroll
  for (int o = 32; o > 0; o >>= 1) {
    anyE |= __shfl_xor((int)anyE, o);
    anyN |= __shfl_xor((int)anyN, o);
  }
  __shared__ int sE, sN;
  if (tid == 0) { sE = 0; sN = 0; }
  __syncthreads();
  if ((tid & 63) == 0) {
    if (anyE) atomicOr(&sE, (int)anyE);
    if (anyN) atomicOr(&sN, (int)anyN);
  }
  __syncthreads();
  if (tid == 0) {
    if (sE) atomicOr(&flagsE[b], sE);
    if (sN) atomicOr(&flagsN[b], sN);
  }
}

// Pass 2: read mask (L3-resident) + flags, write the full output.
__global__ __launch_bounds__(THREADS) void emit_kernel(
    const uint32_t* __restrict__ mask, const int* __restrict__ flagsE,
    const int* __restrict__ flagsN, float* __restrict__ out) {
  const int b     = blockIdx.x / BLOCKS_PER_BATCH;
  const int chunk = blockIdx.x % BLOCKS_PER_BATCH;
  const int tid   = threadIdx.x;

  const int fE = flagsE[b], fN = flagsN[b];

  uint32_t relmask[C];  // per-channel rel-bit mask replicated to 4 bytes
#pragma unroll
  for (int c = 0; c < C; ++c) {
    const bool all_empty = ((fN >> c) & 1) == 0;
    uint32_t rm = 0;
    if (all_empty) {
      if (((fE >> REL0c[c]) & 1) == 0) rm |= 1u << REL0c[c];
      if (((fE >> REL1c[c]) & 1) == 0) rm |= 1u << REL1c[c];
    }
    relmask[c] = rm * 0x01010101u;
  }

  const size_t vb4 = (size_t)chunk * V4_PER_BLOCK;
  const uint32_t* mb = mask + (size_t)b * CH_VEC4;
  f4* ob = reinterpret_cast<f4*>(out) + (size_t)b * C * CH_VEC4;

  for (int it = 0; it < ITERS; ++it) {
    const size_t i4 = vb4 + (size_t)it * THREADS + tid;
    const uint32_t m = mb[i4];
#pragma unroll
    for (int c = 0; c < C; ++c) {
      const uint32_t t = m & relmask[c];
      f4 r;
      r.x = (t & 0x000000ffu) ? 0.f : EMPTY_VAL;
      r.y = (t & 0x0000ff00u) ? 0.f : EMPTY_VAL;
      r.z = (t & 0x00ff0000u) ? 0.f : EMPTY_VAL;
      r.w = (t & 0xff000000u) ? 0.f : EMPTY_VAL;
      __builtin_nontemporal_store(r, ob + ((size_t)c * CH_VEC4 + i4));
    }
  }
}

// ---------------- fallback path (R1, proven): used only if ws too small ----
constexpr int FB_V4_PER_THREAD = 16;
constexpr int FB_BLOCK_VEC4    = THREADS * FB_V4_PER_THREAD;   // 4096
constexpr int FB_BLOCKS_PER_CH = CH_VEC4 / FB_BLOCK_VEC4;      // 128
constexpr int NCH              = B * C;                        // 64
constexpr int FB_TOTAL_BLOCKS  = NCH * FB_BLOCKS_PER_CH;       // 8192

__global__ __launch_bounds__(THREADS) void fb_flags_kernel(
    const float* __restrict__ x, int* __restrict__ flags) {
  const int blk   = blockIdx.x;
  const int ch    = blk / FB_BLOCKS_PER_CH;
  const int chunk = blk % FB_BLOCKS_PER_CH;
  const int tid   = threadIdx.x;
  const float4* p = reinterpret_cast<const float4*>(x) +
                    (size_t)ch * CH_VEC4 + (size_t)chunk * FB_BLOCK_VEC4;
  bool any_empty = false, any_nonempty = false;
#pragma unroll
  for (int i = 0; i < FB_V4_PER_THREAD; ++i) {
    float4 v = p[tid + i * THREADS];
    const bool e0 = (v.x == EMPTY_VAL), e1 = (v.y == EMPTY_VAL);
    const bool e2 = (v.z == EMPTY_VAL), e3 = (v.w == EMPTY_VAL);
    any_empty    |= (e0 | e1 | e2 | e3);
    any_nonempty |= (!e0 | !e1 | !e2 | !e3);
  }
  const bool we = __any(any_empty);
  const bool wn = __any(any_nonempty);
  __shared__ int s_e, s_n;
  if (tid == 0) { s_e = 0; s_n = 0; }
  __syncthreads();
  if ((tid & 63) == 0) {
    if (we) atomicOr(&s_e, 1);
    if (wn) atomicOr(&s_n, 1);
  }
  __syncthreads();
  if (tid == 0) {
    if (s_e) atomicOr(&flags[ch * 2 + 0], 1);
    if (s_n) atomicOr(&flags[ch * 2 + 1], 1);
  }
}

__global__ __launch_bounds__(THREADS) void fb_out_kernel(
    const float* __restrict__ x, const int* __restrict__ flags,
    float* __restrict__ out) {
  const int blk   = blockIdx.x;
  const int ch    = blk / FB_BLOCKS_PER_CH;
  const int chunk = blk % FB_BLOCKS_PER_CH;
  const int b     = ch >> 3;
  const int c     = ch & 7;
  const int tid   = threadIdx.x;
  const size_t base = (size_t)ch * CH_VEC4 + (size_t)chunk * FB_BLOCK_VEC4;
  float4* o = reinterpret_cast<float4*>(out) + base;
  const float4 empty4 = make_float4(EMPTY_VAL, EMPTY_VAL, EMPTY_VAL, EMPTY_VAL);
  const bool all_empty = (flags[ch * 2 + 1] == 0);
  if (!all_empty) {
#pragma unroll
    for (int i = 0; i < FB_V4_PER_THREAD; ++i) o[tid + i * THREADS] = empty4;
    return;
  }
  const int r0 = REL0c[c], r1 = REL1c[c];
  const bool v0 = (flags[(b * 8 + r0) * 2 + 0] == 0);
  const bool v1 = (flags[(b * 8 + r1) * 2 + 0] == 0);
  if (!v0 && !v1) {
#pragma unroll
    for (int i = 0; i < FB_V4_PER_THREAD; ++i) o[tid + i * THREADS] = empty4;
    return;
  }
  const float4* p0 = reinterpret_cast<const float4*>(x) +
                     ((size_t)(b * 8 + r0) * CH_VEC4 + (size_t)chunk * FB_BLOCK_VEC4);
  const float4* p1 = reinterpret_cast<const float4*>(x) +
                     ((size_t)(b * 8 + r1) * CH_VEC4 + (size_t)chunk * FB_BLOCK_VEC4);
  const float4 zero4 = make_float4(0.f, 0.f, 0.f, 0.f);
#pragma unroll
  for (int i = 0; i < FB_V4_PER_THREAD; ++i) {
    const int idx = tid + i * THREADS;
    const float4 a = v0 ? p0[idx] : zero4;
    const float4 q = v1 ? p1[idx] : zero4;
    float4 r;
    r.x = (a.x > 0.f || q.x > 0.f) ? 0.f : EMPTY_VAL;
    r.y = (a.y > 0.f || q.y > 0.f) ? 0.f : EMPTY_VAL;
    r.z = (a.z > 0.f || q.z > 0.f) ? 0.f : EMPTY_VAL;
    r.w = (a.w > 0.f || q.w > 0.f) ? 0.f : EMPTY_VAL;
    o[idx] = r;
  }
}

extern "C" void kernel_launch(void* const* d_in, const int* in_sizes, int n_in,
                              void* d_out, int out_size, void* d_ws, size_t ws_size,
                              hipStream_t stream) {
  const float* x = (const float*)d_in[0];
  float* out     = (float*)d_out;

  const size_t mask_bytes = (size_t)B * CH_VEC4 * sizeof(uint32_t);  // 16 MiB
  if (ws_size >= mask_bytes + 64) {
    uint32_t* mask = (uint32_t*)d_ws;
    int* flagsE    = (int*)((char*)d_ws + mask_bytes);
    int* flagsN    = flagsE + 8;
    (void)hipMemsetAsync(flagsE, 0, 16 * sizeof(int), stream);
    mask_kernel<<<GRID, THREADS, 0, stream>>>(x, mask, flagsE, flagsN);
    emit_kernel<<<GRID, THREADS, 0, stream>>>(mask, flagsE, flagsN, out);
  } else {
    int* flags = (int*)d_ws;
    (void)hipMemsetAsync(flags, 0, NCH * 2 * sizeof(int), stream);
    fb_flags_kernel<<<FB_TOTAL_BLOCKS, THREADS, 0, stream>>>(x, flags);
    fb_out_kernel<<<FB_TOTAL_BLOCKS, THREADS, 0, stream>>>(x, flags, out);
  }
}